// Round 17
// baseline (151.725 us; speedup 1.0000x reference)
//
#include <hip/hip_runtime.h>
#include <hip/hip_bf16.h>
#include <cstdint>
#include <cstddef>

#define B_ 4
#define N_ 4096
#define D_ 1024
#define K_ 256
#define M_ (B_ * N_)          // 16384 rows
#define P_ (6 * K_)           // 1536 proj cols
#define DK2_ (2 * K_)         // 512 rho cols

static __device__ __forceinline__ float sigm(float x) {
    return 1.0f / (1.0f + __expf(-x));
}
static __device__ __forceinline__ float softplusf_(float x) {
    return fmaxf(x, 0.0f) + __logf(1.0f + __expf(-fabsf(x)));
}
static __device__ __forceinline__ unsigned short f2bf(float f) {
    uint32_t u = __float_as_uint(f);
    uint32_t r = (u + 0x7FFFu + ((u >> 16) & 1u)) >> 16;
    return (unsigned short)r;
}

#define GATE_BIAS 0.6190392084062235f
#define AMP_MAX 3.0f

typedef __attribute__((ext_vector_type(8))) __bf16 bf16x8;
typedef __attribute__((ext_vector_type(4))) float f32x4;

// async global->LDS, 16B per lane; lds dest must be wave-uniform base (HW adds lane*16)
static __device__ __forceinline__ void gload_lds16(const unsigned short* g, unsigned short* l) {
    __builtin_amdgcn_global_load_lds(
        (const __attribute__((address_space(1))) void*)g,
        (__attribute__((address_space(3))) void*)l, 16, 0, 0);
}

// ---------------- fp32 -> bf16 convert: x, Wp, Wr in ONE launch ----------------
__global__ __launch_bounds__(256) void cvt3_kernel(const float* __restrict__ s0,
                                                   unsigned short* __restrict__ d0, int n0_,
                                                   const float* __restrict__ s1,
                                                   unsigned short* __restrict__ d1, int n1_,
                                                   const float* __restrict__ s2,
                                                   unsigned short* __restrict__ d2) {
    int i = blockIdx.x * 256 + threadIdx.x;
    const float* s;
    unsigned short* d;
    int j;
    if (i < n0_)            { s = s0; d = d0; j = i; }
    else if (i < n0_ + n1_) { s = s1; d = d1; j = i - n0_; }
    else                    { s = s2; d = d2; j = i - n0_ - n1_; }
    float4 v = reinterpret_cast<const float4*>(s)[j];
    ushort4 o;
    o.x = f2bf(v.x); o.y = f2bf(v.y); o.z = f2bf(v.z); o.w = f2bf(v.w);
    reinterpret_cast<ushort4*>(d)[j] = o;
}

// ---------------- bf16 GEMM, C[M][N] = A[M][Kd] * B[N][Kd]^T ----------------
// r8-proven core, generalized over (THREADS, MINW, BM, BN, WM, WN).
// GEMM1 (round-17 change): (256,1,256,192,2,2) -> wave tile 128x96.
//   Mechanism: all prior configs were LDS-port + MFMA SUM-bound (never
//   overlapped); the fix is arithmetic intensity, not scheduling. 128x96
//   wave tile: 14 ds_read_b128 feed 48 MFMAs per kk (0.021 LDS-B/FLOP vs
//   0.029 before); each read batch is followed by a ~930-cyc MFMA burst
//   that dwarfs read latency, so the compiler's serial read->MFMA schedule
//   is cheap. acc[8][6] = 192 VGPR + 56 frag, ~275 arch-VGPR < 512 spill
//   line; 4 waves, 112 KB LDS, 1 block/CU, grid 64x8=512 = 2 exact rounds.
// GEMM2: unchanged (512,2,256,256,2,4).
// Per tile: stage next tile (gload_lds, pre-swizzled source), read frags
// (plain loads -> compiler-counted lgkmcnt), MFMA w/ setprio,
// vmcnt(0)+lgkmcnt(0), s_barrier. XOR swizzle both sides -> 0 conflicts.

// swizzled fragment read: row r, k-col kc (element units) from [rows]x64 tile
#define FRAG(BUF, r, kc) \
    (*reinterpret_cast<const bf16x8*>(&(BUF)[(size_t)(r) * 64 + (((((kc) >> 3) ^ ((r) & 7)) << 3))]))

template <int THREADS, int MINW, int BM, int BN, int WM, int WN, bool ADD_BIAS, bool SCALE, typename OutT>
__global__ __launch_bounds__(THREADS, MINW) void gemm_bt(const unsigned short* __restrict__ A,
                                                         const unsigned short* __restrict__ Bm,
                                                         const float* __restrict__ bias,
                                                         const float* __restrict__ scale_p,
                                                         OutT* __restrict__ C, int M, int N, int Kd) {
    constexpr int WROW = BM / WM;      // wave row extent
    constexpr int WCOL = BN / WN;      // wave column extent
    constexpr int MR = WROW / 16;      // A-frags per wave
    constexpr int NBF = WCOL / 16;     // B-frags per wave
    constexpr int RPG = THREADS / 8;   // rows staged per group
    constexpr int GA = BM / RPG;       // A stage groups
    constexpr int GB = BN / RPG;       // B stage groups
    __shared__ unsigned short As0[BM * 64];
    __shared__ unsigned short Bs0[BN * 64];
    __shared__ unsigned short As1[BM * 64];
    __shared__ unsigned short Bs1[BN * 64];

    const int tid = threadIdx.x;
    const int w = tid >> 6, l = tid & 63;
    const int m0 = blockIdx.x * BM;
    const int n0 = blockIdx.y * BN;
    const int wm = w / WN, wn = w % WN;
    const int lr = l & 15, lk = (l >> 4) * 8;
    const int nt = Kd >> 6;            // 16 (GEMM1) / 8 (GEMM2), even

    // staging geometry: group G covers rows G*RPG+srow, 8 slots of 8 elems
    const int srow = tid >> 3;         // 0..RPG-1
    const int sslot = tid & 7;
    const int wbase = tid & ~63;
    const int acol = (sslot ^ (srow & 7)) << 3;   // swizzled elem col in row

    f32x4 acc[MR][NBF];
#pragma unroll
    for (int mi = 0; mi < MR; ++mi)
#pragma unroll
        for (int ni = 0; ni < NBF; ++ni) acc[mi][ni] = (f32x4){0.f, 0.f, 0.f, 0.f};

#define STAGE_ALL(PA, PB, K0)                                                         \
    {                                                                                 \
        _Pragma("unroll") for (int g = 0; g < GA; ++g) {                              \
            int row = g * RPG + srow;                                                 \
            gload_lds16(A + (size_t)(m0 + row) * Kd + (K0) + acol,                    \
                        (PA) + (size_t)(g * (THREADS * 8)) + (size_t)wbase * 8);      \
        }                                                                             \
        _Pragma("unroll") for (int g = 0; g < GB; ++g) {                              \
            int row = g * RPG + srow;                                                 \
            gload_lds16(Bm + (size_t)(n0 + row) * Kd + (K0) + acol,                   \
                        (PB) + (size_t)(g * (THREADS * 8)) + (size_t)wbase * 8);      \
        }                                                                             \
    }

#define TILE_STEP(T, CA, CB, PA, PB)                                                  \
    {                                                                                 \
        if ((T) + 1 < nt) STAGE_ALL(PA, PB, ((T) + 1) * 64);                          \
        _Pragma("unroll") for (int kkI = 0; kkI < 2; ++kkI) {                         \
            const int kk = kkI * 32;                                                  \
            bf16x8 af[MR], bfr[NBF];                                                  \
            _Pragma("unroll") for (int f = 0; f < MR; ++f) {                          \
                int ar = wm * WROW + f * 16 + lr;                                     \
                af[f] = FRAG(CA, ar, kk + lk);                                        \
            }                                                                         \
            _Pragma("unroll") for (int f = 0; f < NBF; ++f) {                         \
                int br = wn * WCOL + f * 16 + lr;                                     \
                bfr[f] = FRAG(CB, br, kk + lk);                                       \
            }                                                                         \
            __builtin_amdgcn_s_setprio(1);                                            \
            _Pragma("unroll") for (int mi = 0; mi < MR; ++mi)                         \
                _Pragma("unroll") for (int ni = 0; ni < NBF; ++ni)                    \
                    acc[mi][ni] = __builtin_amdgcn_mfma_f32_16x16x32_bf16(            \
                        af[mi], bfr[ni], acc[mi][ni], 0, 0, 0);                       \
            __builtin_amdgcn_s_setprio(0);                                            \
        }                                                                             \
        asm volatile("s_waitcnt vmcnt(0) lgkmcnt(0)" ::: "memory");                   \
        __builtin_amdgcn_s_barrier();                                                 \
    }

    // prologue: stage tile 0 into dbuf0, drain, barrier
    STAGE_ALL(As0, Bs0, 0);
    asm volatile("s_waitcnt vmcnt(0)" ::: "memory");
    __builtin_amdgcn_s_barrier();

    for (int t = 0; t < nt; t += 2) {
        TILE_STEP(t, As0, Bs0, As1, Bs1);
        TILE_STEP(t + 1, As1, Bs1, As0, Bs0);
    }

    float sc = SCALE ? *scale_p : 1.0f;
#pragma unroll
    for (int mi = 0; mi < MR; ++mi) {
        int row = m0 + wm * WROW + mi * 16 + (l >> 4) * 4;
#pragma unroll
        for (int ni = 0; ni < NBF; ++ni) {
            int col = n0 + wn * WCOL + ni * 16 + lr;
            float bv = ADD_BIAS ? bias[col] : 0.0f;
#pragma unroll
            for (int j = 0; j < 4; ++j) {
                float v = acc[mi][ni][j] + bv;
                if (SCALE) v *= sc;
                C[(size_t)(row + j) * N + col] = (OutT)v;
            }
        }
    }
#undef STAGE_ALL
#undef TILE_STEP
}

// ---------------- per-step oscillator math (fp16 raw) ----------------
struct Step {
    float alpha, dr, di, cs, sn, g, beta;
};
template <bool FULL>
static __device__ __forceinline__ Step compute_step(const _Float16* __restrict__ p, float pos) {
    Step s;
    float a_raw = (float)p[0];
    float o_raw = (float)p[K_];
    float phi   = (float)p[2 * K_];
    float al    = (float)p[3 * K_];
    float A     = AMP_MAX * sigm(a_raw);
    float omega = softplusf_(o_raw);
    float alpha = sigm(al + GATE_BIAS);
    float angle = omega * pos + phi;
    float sn, cs;
    __sincosf(angle, &sn, &cs);
    float oma = 1.0f - alpha;
    s.alpha = alpha;
    s.dr = oma * A * cs;
    s.di = oma * A * sn;
    s.cs = cs;
    s.sn = sn;
    if (FULL) {
        s.g    = sigm((float)p[4 * K_]);
        s.beta = sigm((float)p[5 * K_]);
    }
    return s;
}

// ---------------- scan stage 1: chunk + sub-chunk summaries ----------------
// grid: (chunk=16, kgroup=16, b=4); block: 256 = 16 channels x 16 sub-chunks of 16 steps
__global__ __launch_bounds__(256) void scan_sum_kernel(const _Float16* __restrict__ raw,
                                                       float* __restrict__ sA,
                                                       float* __restrict__ sR,
                                                       float* __restrict__ sI,
                                                       float* __restrict__ subA,
                                                       float* __restrict__ subR,
                                                       float* __restrict__ subI) {
    const int tid = threadIdx.x;
    const int c = tid & 15, t = tid >> 4;
    const int chunk = blockIdx.x, kg = blockIdx.y, b = blockIdx.z;
    const int k = kg * 16 + c;
    const int n0 = chunk * 256 + t * 16;
    const _Float16* base = raw + (size_t)(b * N_ + n0) * P_ + k;

    float aP = 1.0f, rR = 0.0f, rI = 0.0f;
#pragma unroll
    for (int j = 0; j < 16; ++j) {
        Step s = compute_step<false>(base + (size_t)j * P_, __logf((float)(n0 + j + 1)));
        aP *= s.alpha;
        rR = s.alpha * rR + s.dr;
        rI = s.alpha * rI + s.di;
    }
    // sub-chunk summary -> global (consumed by scan_apply instead of recompute)
    const int chan = b * K_ + kg * 16 + c;
    const int sidx = (chunk * 16 + t) * 1024 + chan;
    subA[sidx] = aP;
    subR[sidx] = rR;
    subI[sidx] = rI;

    __shared__ float lA[256], lR[256], lI[256];
    lA[c * 16 + t] = aP;
    lR[c * 16 + t] = rR;
    lI[c * 16 + t] = rI;
    __syncthreads();
    if (tid < 16) {
        float a = 1.0f, r = 0.0f, im = 0.0f;
        for (int tt = 0; tt < 16; ++tt) {
            float at = lA[tid * 16 + tt];
            r  = at * r  + lR[tid * 16 + tt];
            im = at * im + lI[tid * 16 + tt];
            a *= at;
        }
        int chanw = b * K_ + kg * 16 + tid;
        sA[chunk * 1024 + chanw] = a;
        sR[chunk * 1024 + chanw] = r;
        sI[chunk * 1024 + chanw] = im;
    }
}

// ---------------- scan stage 2: apply + postprocess -> rho (bf16) ----------------
__global__ __launch_bounds__(256) void scan_apply_kernel(const _Float16* __restrict__ raw,
                                                         const float* __restrict__ sA,
                                                         const float* __restrict__ sR,
                                                         const float* __restrict__ sI,
                                                         const float* __restrict__ subA,
                                                         const float* __restrict__ subR,
                                                         const float* __restrict__ subI,
                                                         unsigned short* __restrict__ rho) {
    const int tid = threadIdx.x;
    const int c = tid & 15, t = tid >> 4;
    const int chunk = blockIdx.x, kg = blockIdx.y, b = blockIdx.z;
    const int k = kg * 16 + c;
    const int n0 = chunk * 256 + t * 16;
    const _Float16* base = raw + (size_t)(b * N_ + n0) * P_ + k;

    // chunk-prefix (exclusive) for channel handled by lanes tid<16
    float pR = 0.0f, pI = 0.0f;
    if (tid < 16) {
        int chan = b * K_ + kg * 16 + tid;
        for (int ch = 0; ch < chunk; ++ch) {
            float a = sA[ch * 1024 + chan];
            pR = a * pR + sR[ch * 1024 + chan];
            pI = a * pI + sI[ch * 1024 + chan];
        }
    }
    // sub-chunk summaries from scan_sum (replaces recompute pass)
    __shared__ float lA[256], lR[256], lI[256], pTR[256], pTI[256];
    {
        const int chan = b * K_ + kg * 16 + c;
        const int sidx = (chunk * 16 + t) * 1024 + chan;
        lA[c * 16 + t] = subA[sidx];
        lR[c * 16 + t] = subR[sidx];
        lI[c * 16 + t] = subI[sidx];
    }
    __syncthreads();
    if (tid < 16) {
        float r = pR, im = pI;
        for (int tt = 0; tt < 16; ++tt) {
            pTR[tid * 16 + tt] = r;
            pTI[tid * 16 + tt] = im;
            float at = lA[tid * 16 + tt];
            r  = at * r  + lR[tid * 16 + tt];
            im = at * im + lI[tid * 16 + tt];
        }
    }
    __syncthreads();
    // seeded walk + postprocess
    float r = pTR[c * 16 + t], im = pTI[c * 16 + t];
    unsigned short* orow = rho + (size_t)(b * N_ + n0) * DK2_ + k;
#pragma unroll
    for (int j = 0; j < 16; ++j) {
        Step s = compute_step<true>(base + (size_t)j * P_, __logf((float)(n0 + j + 1)));
        r  = s.alpha * r  + s.dr;
        im = s.alpha * im + s.di;
        float readout = r * s.cs + im * s.sn;
        float r2 = r  - s.beta * readout * s.cs;
        float i3 = im - s.beta * readout * s.sn;
        float mod = __fsqrt_rn(r2 * r2 + i3 * i3 + 1e-8f);
        float scl = fmaxf(mod, 1.0f);
        float inv = 1.0f / scl;
        float rr = r2 * inv, ri = i3 * inv;
        float rho_re = rr * s.cs + ri * s.sn;
        float rho_im = -rr * s.sn + ri * s.cs;
        orow[(size_t)j * DK2_]      = f2bf(s.g * rho_re);
        orow[(size_t)j * DK2_ + K_] = f2bf(s.g * rho_im);
    }
}

extern "C" void kernel_launch(void* const* d_in, const int* in_sizes, int n_in,
                              void* d_out, int out_size, void* d_ws, size_t ws_size,
                              hipStream_t stream) {
    const float* x  = (const float*)d_in[0];
    const float* Wp = (const float*)d_in[1];
    const float* bp = (const float*)d_in[2];
    const float* Wr = (const float*)d_in[3];
    const float* rs = (const float*)d_in[4];
    float* out = (float*)d_out;
    char* ws = (char*)d_ws;

    // workspace layout (bytes)
    _Float16* raw = (_Float16*)ws;                               // 50,331,648
    unsigned short* xb  = (unsigned short*)(ws + 100663296);     // 33,554,432
    unsigned short* wpb = (unsigned short*)(ws + 134217728);     // 3,145,728 (dead after GEMM1)
    unsigned short* wrb = (unsigned short*)(ws + 137363456);     // 1,048,576
    float* sA = (float*)(ws + 138412032);                        // 65,536
    float* sR = (float*)(ws + 138477568);                        // 65,536
    float* sI = (float*)(ws + 138543104);                        // 65,536
    unsigned short* rho = xb;            // alias: x_bf16 dead after GEMM1
    float* subA = (float*)(ws + 134217728);                      // alias wpb: 1 MB
    float* subR = (float*)(ws + 135266304);                      // 1 MB
    float* subI = (float*)(ws + 136314880);                      // 1 MB (ends at wrb)

    // all three converts, one launch: x (4,194,304 f4) + Wp (393,216) + Wr (131,072)
    cvt3_kernel<<<(4194304 + 393216 + 131072 + 255) / 256, 256, 0, stream>>>(
        x, xb, M_ * D_ / 4, Wp, wpb, P_ * D_ / 4, Wr, wrb);

    // GEMM1: 256x192 tile, 4 waves (2x2), wave tile 128x96 (area/perimeter lever)
    gemm_bt<256, 1, 256, 192, 2, 2, true, false, _Float16>
        <<<dim3(M_ / 256, P_ / 192), 256, 0, stream>>>(
        xb, wpb, bp, nullptr, raw, M_, P_, D_);

    scan_sum_kernel<<<dim3(16, 16, 4), 256, 0, stream>>>(raw, sA, sR, sI, subA, subR, subI);
    scan_apply_kernel<<<dim3(16, 16, 4), 256, 0, stream>>>(raw, sA, sR, sI, subA, subR, subI, rho);

    // GEMM2: unchanged r8 config (512 thr, 256x256, 2x4 waves)
    gemm_bt<512, 2, 256, 256, 2, 4, false, true, float>
        <<<dim3(M_ / 256, D_ / 256), 512, 0, stream>>>(
        rho, wrb, nullptr, rs, out, M_, D_, DK2_);
}

// Round 18
// 148.407 us; speedup vs baseline: 1.0224x; 1.0224x over previous
//
#include <hip/hip_runtime.h>
#include <hip/hip_bf16.h>
#include <cstdint>
#include <cstddef>

#define B_ 4
#define N_ 4096
#define D_ 1024
#define K_ 256
#define M_ (B_ * N_)          // 16384 rows
#define P_ (6 * K_)           // 1536 proj cols
#define DK2_ (2 * K_)         // 512 rho cols

static __device__ __forceinline__ float sigm(float x) {
    return 1.0f / (1.0f + __expf(-x));
}
static __device__ __forceinline__ float softplusf_(float x) {
    return fmaxf(x, 0.0f) + __logf(1.0f + __expf(-fabsf(x)));
}
static __device__ __forceinline__ unsigned short f2bf(float f) {
    uint32_t u = __float_as_uint(f);
    uint32_t r = (u + 0x7FFFu + ((u >> 16) & 1u)) >> 16;
    return (unsigned short)r;
}

#define GATE_BIAS 0.6190392084062235f
#define AMP_MAX 3.0f

typedef __attribute__((ext_vector_type(8))) __bf16 bf16x8;
typedef __attribute__((ext_vector_type(4))) float f32x4;

// async global->LDS, 16B per lane; lds dest must be wave-uniform base (HW adds lane*16)
static __device__ __forceinline__ void gload_lds16(const unsigned short* g, unsigned short* l) {
    __builtin_amdgcn_global_load_lds(
        (const __attribute__((address_space(1))) void*)g,
        (__attribute__((address_space(3))) void*)l, 16, 0, 0);
}

// ---------------- fp32 -> bf16 convert: x, Wp, Wr in ONE launch ----------------
__global__ __launch_bounds__(256) void cvt3_kernel(const float* __restrict__ s0,
                                                   unsigned short* __restrict__ d0, int n0_,
                                                   const float* __restrict__ s1,
                                                   unsigned short* __restrict__ d1, int n1_,
                                                   const float* __restrict__ s2,
                                                   unsigned short* __restrict__ d2) {
    int i = blockIdx.x * 256 + threadIdx.x;
    const float* s;
    unsigned short* d;
    int j;
    if (i < n0_)            { s = s0; d = d0; j = i; }
    else if (i < n0_ + n1_) { s = s1; d = d1; j = i - n0_; }
    else                    { s = s2; d = d2; j = i - n0_ - n1_; }
    float4 v = reinterpret_cast<const float4*>(s)[j];
    ushort4 o;
    o.x = f2bf(v.x); o.y = f2bf(v.y); o.z = f2bf(v.z); o.w = f2bf(v.w);
    reinterpret_cast<ushort4*>(d)[j] = o;
}

// ---------------- bf16 GEMM, C[M][N] = A[M][Kd] * B[N][Kd]^T ----------------
// r8-exact core (proven best: GEMM1 62.5-64 us): 256 x BN tile, BK=64,
// 8 waves (2M x 4N), wave tile 128 x BN/4, 2 static dbufs, one barrier per
// K-tile. Round-18 addition: T1 XCD-aware bijective block swizzle (1D grid,
// nwg % 8 == 0 for both GEMMs: 512, 256). Consecutive same-XCD blocks are
// consecutive row-tiles sharing the B panel -> L2-local. Pure index remap,
// correctness-safe by construction.
// Per tile: stage next tile (gload_lds, pre-swizzled source), read frags
// (plain loads -> compiler-counted lgkmcnt), MFMA w/ setprio,
// vmcnt(0)+lgkmcnt(0), s_barrier. XOR swizzle both sides -> 0 conflicts.

// swizzled fragment read: row r, k-col kc (element units) from [rows]x64 tile
#define FRAG(BUF, r, kc) \
    (*reinterpret_cast<const bf16x8*>(&(BUF)[(size_t)(r) * 64 + (((((kc) >> 3) ^ ((r) & 7)) << 3))]))

template <int BN, bool ADD_BIAS, bool SCALE, typename OutT>
__global__ __launch_bounds__(512, 2) void gemm_bt(const unsigned short* __restrict__ A,
                                                  const unsigned short* __restrict__ Bm,
                                                  const float* __restrict__ bias,
                                                  const float* __restrict__ scale_p,
                                                  OutT* __restrict__ C, int M, int N, int Kd) {
    constexpr int NB = BN / 64;        // B-frags per wave
    constexpr int WCOL = BN / 4;       // wave column extent
    __shared__ unsigned short As0[256 * 64];
    __shared__ unsigned short Bs0[BN * 64];
    __shared__ unsigned short As1[256 * 64];
    __shared__ unsigned short Bs1[BN * 64];

    const int tid = threadIdx.x;
    const int w = tid >> 6, l = tid & 63;
    // T1: XCD-aware bijective swizzle of the flattened block index
    const int nwg = gridDim.x;
    int bid = blockIdx.x;
    bid = (bid & 7) * (nwg >> 3) + (bid >> 3);
    const int mt = M / 256;            // row tiles
    const int m0 = (bid % mt) * 256;
    const int n0 = (bid / mt) * BN;
    const int wm = w >> 2, wn = w & 3;         // 2 x 4 wave grid
    const int lr = l & 15, lk = (l >> 4) * 8;
    const int nt = Kd >> 6;                    // 16 (GEMM1) / 8 (GEMM2), even

    // staging geometry: group G covers rows G*64+srow, 8 slots of 8 elems
    const int srow = tid >> 3;                 // 0..63
    const int sslot = tid & 7;
    const int wbase = tid & ~63;
    const int acol = (sslot ^ (srow & 7)) << 3;   // swizzled elem col in row

    f32x4 acc[8][NB];
#pragma unroll
    for (int mi = 0; mi < 8; ++mi)
#pragma unroll
        for (int ni = 0; ni < NB; ++ni) acc[mi][ni] = (f32x4){0.f, 0.f, 0.f, 0.f};

#define STAGE_ALL(PA, PB, K0)                                                         \
    {                                                                                 \
        _Pragma("unroll") for (int g = 0; g < 4; ++g) {                               \
            int row = g * 64 + srow;                                                  \
            gload_lds16(A + (size_t)(m0 + row) * Kd + (K0) + acol,                    \
                        (PA) + ((g * 512 + wbase)) * 8);                              \
        }                                                                             \
        _Pragma("unroll") for (int g = 0; g < NB; ++g) {                              \
            int row = g * 64 + srow;                                                  \
            gload_lds16(Bm + (size_t)(n0 + row) * Kd + (K0) + acol,                   \
                        (PB) + ((g * 512 + wbase)) * 8);                              \
        }                                                                             \
    }

#define TILE_STEP(T, CA, CB, PA, PB)                                                  \
    {                                                                                 \
        if ((T) + 1 < nt) STAGE_ALL(PA, PB, ((T) + 1) * 64);                          \
        _Pragma("unroll") for (int kkI = 0; kkI < 2; ++kkI) {                         \
            const int kk = kkI * 32;                                                  \
            bf16x8 af[8], bfr[NB];                                                    \
            _Pragma("unroll") for (int f = 0; f < 8; ++f) {                           \
                int ar = wm * 128 + f * 16 + lr;                                      \
                af[f] = FRAG(CA, ar, kk + lk);                                        \
            }                                                                         \
            _Pragma("unroll") for (int f = 0; f < NB; ++f) {                          \
                int br = wn * WCOL + f * 16 + lr;                                     \
                bfr[f] = FRAG(CB, br, kk + lk);                                       \
            }                                                                         \
            __builtin_amdgcn_s_setprio(1);                                            \
            _Pragma("unroll") for (int mi = 0; mi < 8; ++mi)                          \
                _Pragma("unroll") for (int ni = 0; ni < NB; ++ni)                     \
                    acc[mi][ni] = __builtin_amdgcn_mfma_f32_16x16x32_bf16(            \
                        af[mi], bfr[ni], acc[mi][ni], 0, 0, 0);                       \
            __builtin_amdgcn_s_setprio(0);                                            \
        }                                                                             \
        asm volatile("s_waitcnt vmcnt(0) lgkmcnt(0)" ::: "memory");                   \
        __builtin_amdgcn_s_barrier();                                                 \
    }

    // prologue: stage tile 0 into dbuf0, drain, barrier
    STAGE_ALL(As0, Bs0, 0);
    asm volatile("s_waitcnt vmcnt(0)" ::: "memory");
    __builtin_amdgcn_s_barrier();

    for (int t = 0; t < nt; t += 2) {
        TILE_STEP(t, As0, Bs0, As1, Bs1);
        TILE_STEP(t + 1, As1, Bs1, As0, Bs0);
    }

    float sc = SCALE ? *scale_p : 1.0f;
#pragma unroll
    for (int mi = 0; mi < 8; ++mi) {
        int row = m0 + wm * 128 + mi * 16 + (l >> 4) * 4;
#pragma unroll
        for (int ni = 0; ni < NB; ++ni) {
            int col = n0 + wn * WCOL + ni * 16 + lr;
            float bv = ADD_BIAS ? bias[col] : 0.0f;
#pragma unroll
            for (int j = 0; j < 4; ++j) {
                float v = acc[mi][ni][j] + bv;
                if (SCALE) v *= sc;
                C[(size_t)(row + j) * N + col] = (OutT)v;
            }
        }
    }
#undef STAGE_ALL
#undef TILE_STEP
}

// ---------------- per-step oscillator math (fp16 raw) ----------------
struct Step {
    float alpha, dr, di, cs, sn, g, beta;
};
template <bool FULL>
static __device__ __forceinline__ Step compute_step(const _Float16* __restrict__ p, float pos) {
    Step s;
    float a_raw = (float)p[0];
    float o_raw = (float)p[K_];
    float phi   = (float)p[2 * K_];
    float al    = (float)p[3 * K_];
    float A     = AMP_MAX * sigm(a_raw);
    float omega = softplusf_(o_raw);
    float alpha = sigm(al + GATE_BIAS);
    float angle = omega * pos + phi;
    float sn, cs;
    __sincosf(angle, &sn, &cs);
    float oma = 1.0f - alpha;
    s.alpha = alpha;
    s.dr = oma * A * cs;
    s.di = oma * A * sn;
    s.cs = cs;
    s.sn = sn;
    if (FULL) {
        s.g    = sigm((float)p[4 * K_]);
        s.beta = sigm((float)p[5 * K_]);
    }
    return s;
}

// ---------------- scan stage 1: chunk + sub-chunk summaries ----------------
// grid: (chunk=16, kgroup=16, b=4); block: 256 = 16 channels x 16 sub-chunks of 16 steps
__global__ __launch_bounds__(256) void scan_sum_kernel(const _Float16* __restrict__ raw,
                                                       float* __restrict__ sA,
                                                       float* __restrict__ sR,
                                                       float* __restrict__ sI,
                                                       float* __restrict__ subA,
                                                       float* __restrict__ subR,
                                                       float* __restrict__ subI) {
    const int tid = threadIdx.x;
    const int c = tid & 15, t = tid >> 4;
    const int chunk = blockIdx.x, kg = blockIdx.y, b = blockIdx.z;
    const int k = kg * 16 + c;
    const int n0 = chunk * 256 + t * 16;
    const _Float16* base = raw + (size_t)(b * N_ + n0) * P_ + k;

    float aP = 1.0f, rR = 0.0f, rI = 0.0f;
#pragma unroll
    for (int j = 0; j < 16; ++j) {
        Step s = compute_step<false>(base + (size_t)j * P_, __logf((float)(n0 + j + 1)));
        aP *= s.alpha;
        rR = s.alpha * rR + s.dr;
        rI = s.alpha * rI + s.di;
    }
    // sub-chunk summary -> global (consumed by scan_apply instead of recompute)
    const int chan = b * K_ + kg * 16 + c;
    const int sidx = (chunk * 16 + t) * 1024 + chan;
    subA[sidx] = aP;
    subR[sidx] = rR;
    subI[sidx] = rI;

    __shared__ float lA[256], lR[256], lI[256];
    lA[c * 16 + t] = aP;
    lR[c * 16 + t] = rR;
    lI[c * 16 + t] = rI;
    __syncthreads();
    if (tid < 16) {
        float a = 1.0f, r = 0.0f, im = 0.0f;
        for (int tt = 0; tt < 16; ++tt) {
            float at = lA[tid * 16 + tt];
            r  = at * r  + lR[tid * 16 + tt];
            im = at * im + lI[tid * 16 + tt];
            a *= at;
        }
        int chanw = b * K_ + kg * 16 + tid;
        sA[chunk * 1024 + chanw] = a;
        sR[chunk * 1024 + chanw] = r;
        sI[chunk * 1024 + chanw] = im;
    }
}

// ---------------- scan stage 2: apply + postprocess -> rho (bf16) ----------------
__global__ __launch_bounds__(256) void scan_apply_kernel(const _Float16* __restrict__ raw,
                                                         const float* __restrict__ sA,
                                                         const float* __restrict__ sR,
                                                         const float* __restrict__ sI,
                                                         const float* __restrict__ subA,
                                                         const float* __restrict__ subR,
                                                         const float* __restrict__ subI,
                                                         unsigned short* __restrict__ rho) {
    const int tid = threadIdx.x;
    const int c = tid & 15, t = tid >> 4;
    const int chunk = blockIdx.x, kg = blockIdx.y, b = blockIdx.z;
    const int k = kg * 16 + c;
    const int n0 = chunk * 256 + t * 16;
    const _Float16* base = raw + (size_t)(b * N_ + n0) * P_ + k;

    // chunk-prefix (exclusive) for channel handled by lanes tid<16
    float pR = 0.0f, pI = 0.0f;
    if (tid < 16) {
        int chan = b * K_ + kg * 16 + tid;
        for (int ch = 0; ch < chunk; ++ch) {
            float a = sA[ch * 1024 + chan];
            pR = a * pR + sR[ch * 1024 + chan];
            pI = a * pI + sI[ch * 1024 + chan];
        }
    }
    // sub-chunk summaries from scan_sum (replaces recompute pass)
    __shared__ float lA[256], lR[256], lI[256], pTR[256], pTI[256];
    {
        const int chan = b * K_ + kg * 16 + c;
        const int sidx = (chunk * 16 + t) * 1024 + chan;
        lA[c * 16 + t] = subA[sidx];
        lR[c * 16 + t] = subR[sidx];
        lI[c * 16 + t] = subI[sidx];
    }
    __syncthreads();
    if (tid < 16) {
        float r = pR, im = pI;
        for (int tt = 0; tt < 16; ++tt) {
            pTR[tid * 16 + tt] = r;
            pTI[tid * 16 + tt] = im;
            float at = lA[tid * 16 + tt];
            r  = at * r  + lR[tid * 16 + tt];
            im = at * im + lI[tid * 16 + tt];
        }
    }
    __syncthreads();
    // seeded walk + postprocess
    float r = pTR[c * 16 + t], im = pTI[c * 16 + t];
    unsigned short* orow = rho + (size_t)(b * N_ + n0) * DK2_ + k;
#pragma unroll
    for (int j = 0; j < 16; ++j) {
        Step s = compute_step<true>(base + (size_t)j * P_, __logf((float)(n0 + j + 1)));
        r  = s.alpha * r  + s.dr;
        im = s.alpha * im + s.di;
        float readout = r * s.cs + im * s.sn;
        float r2 = r  - s.beta * readout * s.cs;
        float i3 = im - s.beta * readout * s.sn;
        float mod = __fsqrt_rn(r2 * r2 + i3 * i3 + 1e-8f);
        float scl = fmaxf(mod, 1.0f);
        float inv = 1.0f / scl;
        float rr = r2 * inv, ri = i3 * inv;
        float rho_re = rr * s.cs + ri * s.sn;
        float rho_im = -rr * s.sn + ri * s.cs;
        orow[(size_t)j * DK2_]      = f2bf(s.g * rho_re);
        orow[(size_t)j * DK2_ + K_] = f2bf(s.g * rho_im);
    }
}

extern "C" void kernel_launch(void* const* d_in, const int* in_sizes, int n_in,
                              void* d_out, int out_size, void* d_ws, size_t ws_size,
                              hipStream_t stream) {
    const float* x  = (const float*)d_in[0];
    const float* Wp = (const float*)d_in[1];
    const float* bp = (const float*)d_in[2];
    const float* Wr = (const float*)d_in[3];
    const float* rs = (const float*)d_in[4];
    float* out = (float*)d_out;
    char* ws = (char*)d_ws;

    // workspace layout (bytes)
    _Float16* raw = (_Float16*)ws;                               // 50,331,648
    unsigned short* xb  = (unsigned short*)(ws + 100663296);     // 33,554,432
    unsigned short* wpb = (unsigned short*)(ws + 134217728);     // 3,145,728 (dead after GEMM1)
    unsigned short* wrb = (unsigned short*)(ws + 137363456);     // 1,048,576
    float* sA = (float*)(ws + 138412032);                        // 65,536
    float* sR = (float*)(ws + 138477568);                        // 65,536
    float* sI = (float*)(ws + 138543104);                        // 65,536
    unsigned short* rho = xb;            // alias: x_bf16 dead after GEMM1
    float* subA = (float*)(ws + 134217728);                      // alias wpb: 1 MB
    float* subR = (float*)(ws + 135266304);                      // 1 MB
    float* subI = (float*)(ws + 136314880);                      // 1 MB (ends at wrb)

    // all three converts, one launch: x (4,194,304 f4) + Wp (393,216) + Wr (131,072)
    cvt3_kernel<<<(4194304 + 393216 + 131072 + 255) / 256, 256, 0, stream>>>(
        x, xb, M_ * D_ / 4, Wp, wpb, P_ * D_ / 4, Wr, wrb);

    // GEMM1: r8-exact config, 1D grid (64*8=512, %8==0) with T1 XCD swizzle
    gemm_bt<192, true, false, _Float16><<<(M_ / 256) * (P_ / 192), 512, 0, stream>>>(
        xb, wpb, bp, nullptr, raw, M_, P_, D_);

    scan_sum_kernel<<<dim3(16, 16, 4), 256, 0, stream>>>(raw, sA, sR, sI, subA, subR, subI);
    scan_apply_kernel<<<dim3(16, 16, 4), 256, 0, stream>>>(raw, sA, sR, sI, subA, subR, subI, rho);

    // GEMM2: r8-exact config, 1D grid (64*4=256, %8==0) with T1 XCD swizzle
    gemm_bt<256, false, true, float><<<(M_ / 256) * (D_ / 256), 512, 0, stream>>>(
        rho, wrb, nullptr, rs, out, M_, D_, DK2_);
}

// Round 19
// 139.229 us; speedup vs baseline: 1.0897x; 1.0659x over previous
//
#include <hip/hip_runtime.h>
#include <hip/hip_bf16.h>
#include <cstdint>
#include <cstddef>

#define B_ 4
#define N_ 4096
#define D_ 1024
#define K_ 256
#define M_ (B_ * N_)          // 16384 rows
#define P_ (6 * K_)           // 1536 proj cols
#define DK2_ (2 * K_)         // 512 rho cols

static __device__ __forceinline__ float sigm(float x) {
    return 1.0f / (1.0f + __expf(-x));
}
static __device__ __forceinline__ float softplusf_(float x) {
    return fmaxf(x, 0.0f) + __logf(1.0f + __expf(-fabsf(x)));
}
static __device__ __forceinline__ unsigned short f2bf(float f) {
    uint32_t u = __float_as_uint(f);
    uint32_t r = (u + 0x7FFFu + ((u >> 16) & 1u)) >> 16;
    return (unsigned short)r;
}

#define GATE_BIAS 0.6190392084062235f
#define AMP_MAX 3.0f

typedef __attribute__((ext_vector_type(8))) __bf16 bf16x8;
typedef __attribute__((ext_vector_type(4))) float f32x4;

// async global->LDS, 16B per lane; lds dest must be wave-uniform base (HW adds lane*16)
static __device__ __forceinline__ void gload_lds16(const unsigned short* g, unsigned short* l) {
    __builtin_amdgcn_global_load_lds(
        (const __attribute__((address_space(1))) void*)g,
        (__attribute__((address_space(3))) void*)l, 16, 0, 0);
}

// ---------------- fp32 -> bf16 convert: x, Wp, Wr in ONE launch ----------------
__global__ __launch_bounds__(256) void cvt3_kernel(const float* __restrict__ s0,
                                                   unsigned short* __restrict__ d0, int n0_,
                                                   const float* __restrict__ s1,
                                                   unsigned short* __restrict__ d1, int n1_,
                                                   const float* __restrict__ s2,
                                                   unsigned short* __restrict__ d2) {
    int i = blockIdx.x * 256 + threadIdx.x;
    const float* s;
    unsigned short* d;
    int j;
    if (i < n0_)            { s = s0; d = d0; j = i; }
    else if (i < n0_ + n1_) { s = s1; d = d1; j = i - n0_; }
    else                    { s = s2; d = d2; j = i - n0_ - n1_; }
    float4 v = reinterpret_cast<const float4*>(s)[j];
    ushort4 o;
    o.x = f2bf(v.x); o.y = f2bf(v.y); o.z = f2bf(v.z); o.w = f2bf(v.w);
    reinterpret_cast<ushort4*>(d)[j] = o;
}

// ---------------- bf16 GEMM, C[M][N] = A[M][Kd] * B[N][Kd]^T ----------------
// r8-exact (proven best: GEMM1 62.5-64 us): 256 x BN tile, BK=64, 8 waves
// (2M x 4N), wave tile 128 x BN/4, 2 static dbufs, one barrier per K-tile.
// Per tile: stage next tile (gload_lds, pre-swizzled source), read frags
// (plain C++ loads -> compiler-counted lgkmcnt), MFMA cluster w/ setprio,
// vmcnt(0)+lgkmcnt(0), s_barrier. Race-free: reads target cur, staging
// targets other; cur overwritten only after the barrier both counters
// drained at. XOR swizzle on both sides (rule 21) -> 0 bank conflicts.
// NOTE r18: T1 XCD-swizzle REGRESSES here (FETCH 45->134 MB) — the default
// dispatch order is already L3-optimal for this shape. Default 2D grid kept.

// swizzled fragment read: row r, k-col kc (element units) from [rows]x64 tile
#define FRAG(BUF, r, kc) \
    (*reinterpret_cast<const bf16x8*>(&(BUF)[(size_t)(r) * 64 + (((((kc) >> 3) ^ ((r) & 7)) << 3))]))

template <int BN, bool ADD_BIAS, bool SCALE, typename OutT>
__global__ __launch_bounds__(512, 2) void gemm_bt(const unsigned short* __restrict__ A,
                                                  const unsigned short* __restrict__ Bm,
                                                  const float* __restrict__ bias,
                                                  const float* __restrict__ scale_p,
                                                  OutT* __restrict__ C, int M, int N, int Kd) {
    constexpr int NB = BN / 64;        // B-frags per wave
    constexpr int WCOL = BN / 4;       // wave column extent
    __shared__ unsigned short As0[256 * 64];
    __shared__ unsigned short Bs0[BN * 64];
    __shared__ unsigned short As1[256 * 64];
    __shared__ unsigned short Bs1[BN * 64];

    const int tid = threadIdx.x;
    const int w = tid >> 6, l = tid & 63;
    const int m0 = blockIdx.x * 256;
    const int n0 = blockIdx.y * BN;
    const int wm = w >> 2, wn = w & 3;         // 2 x 4 wave grid
    const int lr = l & 15, lk = (l >> 4) * 8;
    const int nt = Kd >> 6;                    // 16 (GEMM1) / 8 (GEMM2), even

    // staging geometry: group G covers rows G*64+srow, 8 slots of 8 elems
    const int srow = tid >> 3;                 // 0..63
    const int sslot = tid & 7;
    const int wbase = tid & ~63;
    const int acol = (sslot ^ (srow & 7)) << 3;   // swizzled elem col in row

    f32x4 acc[8][NB];
#pragma unroll
    for (int mi = 0; mi < 8; ++mi)
#pragma unroll
        for (int ni = 0; ni < NB; ++ni) acc[mi][ni] = (f32x4){0.f, 0.f, 0.f, 0.f};

#define STAGE_ALL(PA, PB, K0)                                                         \
    {                                                                                 \
        _Pragma("unroll") for (int g = 0; g < 4; ++g) {                               \
            int row = g * 64 + srow;                                                  \
            gload_lds16(A + (size_t)(m0 + row) * Kd + (K0) + acol,                    \
                        (PA) + ((g * 512 + wbase)) * 8);                              \
        }                                                                             \
        _Pragma("unroll") for (int g = 0; g < NB; ++g) {                              \
            int row = g * 64 + srow;                                                  \
            gload_lds16(Bm + (size_t)(n0 + row) * Kd + (K0) + acol,                   \
                        (PB) + ((g * 512 + wbase)) * 8);                              \
        }                                                                             \
    }

#define TILE_STEP(T, CA, CB, PA, PB)                                                  \
    {                                                                                 \
        if ((T) + 1 < nt) STAGE_ALL(PA, PB, ((T) + 1) * 64);                          \
        _Pragma("unroll") for (int kkI = 0; kkI < 2; ++kkI) {                         \
            const int kk = kkI * 32;                                                  \
            bf16x8 af[8], bfr[NB];                                                    \
            _Pragma("unroll") for (int f = 0; f < 8; ++f) {                           \
                int ar = wm * 128 + f * 16 + lr;                                      \
                af[f] = FRAG(CA, ar, kk + lk);                                        \
            }                                                                         \
            _Pragma("unroll") for (int f = 0; f < NB; ++f) {                          \
                int br = wn * WCOL + f * 16 + lr;                                     \
                bfr[f] = FRAG(CB, br, kk + lk);                                       \
            }                                                                         \
            __builtin_amdgcn_s_setprio(1);                                            \
            _Pragma("unroll") for (int mi = 0; mi < 8; ++mi)                          \
                _Pragma("unroll") for (int ni = 0; ni < NB; ++ni)                     \
                    acc[mi][ni] = __builtin_amdgcn_mfma_f32_16x16x32_bf16(            \
                        af[mi], bfr[ni], acc[mi][ni], 0, 0, 0);                       \
            __builtin_amdgcn_s_setprio(0);                                            \
        }                                                                             \
        asm volatile("s_waitcnt vmcnt(0) lgkmcnt(0)" ::: "memory");                   \
        __builtin_amdgcn_s_barrier();                                                 \
    }

    // prologue: stage tile 0 into dbuf0, drain, barrier
    STAGE_ALL(As0, Bs0, 0);
    asm volatile("s_waitcnt vmcnt(0)" ::: "memory");
    __builtin_amdgcn_s_barrier();

    for (int t = 0; t < nt; t += 2) {
        TILE_STEP(t, As0, Bs0, As1, Bs1);
        TILE_STEP(t + 1, As1, Bs1, As0, Bs0);
    }

    float sc = SCALE ? *scale_p : 1.0f;
#pragma unroll
    for (int mi = 0; mi < 8; ++mi) {
        int row = m0 + wm * 128 + mi * 16 + (l >> 4) * 4;
#pragma unroll
        for (int ni = 0; ni < NB; ++ni) {
            int col = n0 + wn * WCOL + ni * 16 + lr;
            float bv = ADD_BIAS ? bias[col] : 0.0f;
#pragma unroll
            for (int j = 0; j < 4; ++j) {
                float v = acc[mi][ni][j] + bv;
                if (SCALE) v *= sc;
                C[(size_t)(row + j) * N + col] = (OutT)v;
            }
        }
    }
#undef STAGE_ALL
#undef TILE_STEP
}

// ---------------- per-step oscillator math (fp16 raw) ----------------
struct Step {
    float alpha, dr, di, cs, sn, g, beta;
};
template <bool FULL>
static __device__ __forceinline__ Step compute_step(const _Float16* __restrict__ p, float pos) {
    Step s;
    float a_raw = (float)p[0];
    float o_raw = (float)p[K_];
    float phi   = (float)p[2 * K_];
    float al    = (float)p[3 * K_];
    float A     = AMP_MAX * sigm(a_raw);
    float omega = softplusf_(o_raw);
    float alpha = sigm(al + GATE_BIAS);
    float angle = omega * pos + phi;
    float sn, cs;
    __sincosf(angle, &sn, &cs);
    float oma = 1.0f - alpha;
    s.alpha = alpha;
    s.dr = oma * A * cs;
    s.di = oma * A * sn;
    s.cs = cs;
    s.sn = sn;
    if (FULL) {
        s.g    = sigm((float)p[4 * K_]);
        s.beta = sigm((float)p[5 * K_]);
    }
    return s;
}

// ---------------- scan stage 1: chunk + sub-chunk summaries ----------------
// grid: (chunk=16, kgroup=16, b=4); block: 256 = 16 channels x 16 sub-chunks of 16 steps
__global__ __launch_bounds__(256) void scan_sum_kernel(const _Float16* __restrict__ raw,
                                                       float* __restrict__ sA,
                                                       float* __restrict__ sR,
                                                       float* __restrict__ sI,
                                                       float* __restrict__ subA,
                                                       float* __restrict__ subR,
                                                       float* __restrict__ subI) {
    const int tid = threadIdx.x;
    const int c = tid & 15, t = tid >> 4;
    const int chunk = blockIdx.x, kg = blockIdx.y, b = blockIdx.z;
    const int k = kg * 16 + c;
    const int n0 = chunk * 256 + t * 16;
    const _Float16* base = raw + (size_t)(b * N_ + n0) * P_ + k;

    float aP = 1.0f, rR = 0.0f, rI = 0.0f;
#pragma unroll
    for (int j = 0; j < 16; ++j) {
        Step s = compute_step<false>(base + (size_t)j * P_, __logf((float)(n0 + j + 1)));
        aP *= s.alpha;
        rR = s.alpha * rR + s.dr;
        rI = s.alpha * rI + s.di;
    }
    // sub-chunk summary -> global (consumed by scan_apply instead of recompute)
    const int chan = b * K_ + kg * 16 + c;
    const int sidx = (chunk * 16 + t) * 1024 + chan;
    subA[sidx] = aP;
    subR[sidx] = rR;
    subI[sidx] = rI;

    __shared__ float lA[256], lR[256], lI[256];
    lA[c * 16 + t] = aP;
    lR[c * 16 + t] = rR;
    lI[c * 16 + t] = rI;
    __syncthreads();
    if (tid < 16) {
        float a = 1.0f, r = 0.0f, im = 0.0f;
        for (int tt = 0; tt < 16; ++tt) {
            float at = lA[tid * 16 + tt];
            r  = at * r  + lR[tid * 16 + tt];
            im = at * im + lI[tid * 16 + tt];
            a *= at;
        }
        int chanw = b * K_ + kg * 16 + tid;
        sA[chunk * 1024 + chanw] = a;
        sR[chunk * 1024 + chanw] = r;
        sI[chunk * 1024 + chanw] = im;
    }
}

// ---------------- scan stage 2: apply + postprocess -> rho (bf16) ----------------
__global__ __launch_bounds__(256) void scan_apply_kernel(const _Float16* __restrict__ raw,
                                                         const float* __restrict__ sA,
                                                         const float* __restrict__ sR,
                                                         const float* __restrict__ sI,
                                                         const float* __restrict__ subA,
                                                         const float* __restrict__ subR,
                                                         const float* __restrict__ subI,
                                                         unsigned short* __restrict__ rho) {
    const int tid = threadIdx.x;
    const int c = tid & 15, t = tid >> 4;
    const int chunk = blockIdx.x, kg = blockIdx.y, b = blockIdx.z;
    const int k = kg * 16 + c;
    const int n0 = chunk * 256 + t * 16;
    const _Float16* base = raw + (size_t)(b * N_ + n0) * P_ + k;

    // chunk-prefix (exclusive) for channel handled by lanes tid<16
    float pR = 0.0f, pI = 0.0f;
    if (tid < 16) {
        int chan = b * K_ + kg * 16 + tid;
        for (int ch = 0; ch < chunk; ++ch) {
            float a = sA[ch * 1024 + chan];
            pR = a * pR + sR[ch * 1024 + chan];
            pI = a * pI + sI[ch * 1024 + chan];
        }
    }
    // sub-chunk summaries from scan_sum (replaces recompute pass)
    __shared__ float lA[256], lR[256], lI[256], pTR[256], pTI[256];
    {
        const int chan = b * K_ + kg * 16 + c;
        const int sidx = (chunk * 16 + t) * 1024 + chan;
        lA[c * 16 + t] = subA[sidx];
        lR[c * 16 + t] = subR[sidx];
        lI[c * 16 + t] = subI[sidx];
    }
    __syncthreads();
    if (tid < 16) {
        float r = pR, im = pI;
        for (int tt = 0; tt < 16; ++tt) {
            pTR[tid * 16 + tt] = r;
            pTI[tid * 16 + tt] = im;
            float at = lA[tid * 16 + tt];
            r  = at * r  + lR[tid * 16 + tt];
            im = at * im + lI[tid * 16 + tt];
        }
    }
    __syncthreads();
    // seeded walk + postprocess
    float r = pTR[c * 16 + t], im = pTI[c * 16 + t];
    unsigned short* orow = rho + (size_t)(b * N_ + n0) * DK2_ + k;
#pragma unroll
    for (int j = 0; j < 16; ++j) {
        Step s = compute_step<true>(base + (size_t)j * P_, __logf((float)(n0 + j + 1)));
        r  = s.alpha * r  + s.dr;
        im = s.alpha * im + s.di;
        float readout = r * s.cs + im * s.sn;
        float r2 = r  - s.beta * readout * s.cs;
        float i3 = im - s.beta * readout * s.sn;
        float mod = __fsqrt_rn(r2 * r2 + i3 * i3 + 1e-8f);
        float scl = fmaxf(mod, 1.0f);
        float inv = 1.0f / scl;
        float rr = r2 * inv, ri = i3 * inv;
        float rho_re = rr * s.cs + ri * s.sn;
        float rho_im = -rr * s.sn + ri * s.cs;
        orow[(size_t)j * DK2_]      = f2bf(s.g * rho_re);
        orow[(size_t)j * DK2_ + K_] = f2bf(s.g * rho_im);
    }
}

extern "C" void kernel_launch(void* const* d_in, const int* in_sizes, int n_in,
                              void* d_out, int out_size, void* d_ws, size_t ws_size,
                              hipStream_t stream) {
    const float* x  = (const float*)d_in[0];
    const float* Wp = (const float*)d_in[1];
    const float* bp = (const float*)d_in[2];
    const float* Wr = (const float*)d_in[3];
    const float* rs = (const float*)d_in[4];
    float* out = (float*)d_out;
    char* ws = (char*)d_ws;

    // workspace layout (bytes)
    _Float16* raw = (_Float16*)ws;                               // 50,331,648
    unsigned short* xb  = (unsigned short*)(ws + 100663296);     // 33,554,432
    unsigned short* wpb = (unsigned short*)(ws + 134217728);     // 3,145,728 (dead after GEMM1)
    unsigned short* wrb = (unsigned short*)(ws + 137363456);     // 1,048,576
    float* sA = (float*)(ws + 138412032);                        // 65,536
    float* sR = (float*)(ws + 138477568);                        // 65,536
    float* sI = (float*)(ws + 138543104);                        // 65,536
    unsigned short* rho = xb;            // alias: x_bf16 dead after GEMM1
    float* subA = (float*)(ws + 134217728);                      // alias wpb: 1 MB
    float* subR = (float*)(ws + 135266304);                      // 1 MB
    float* subI = (float*)(ws + 136314880);                      // 1 MB (ends at wrb)

    // all three converts, one launch: x (4,194,304 f4) + Wp (393,216) + Wr (131,072)
    cvt3_kernel<<<(4194304 + 393216 + 131072 + 255) / 256, 256, 0, stream>>>(
        x, xb, M_ * D_ / 4, Wp, wpb, P_ * D_ / 4, Wr, wrb);

    gemm_bt<192, true, false, _Float16><<<dim3(M_ / 256, P_ / 192), 512, 0, stream>>>(
        xb, wpb, bp, nullptr, raw, M_, P_, D_);

    scan_sum_kernel<<<dim3(16, 16, 4), 256, 0, stream>>>(raw, sA, sR, sI, subA, subR, subI);
    scan_apply_kernel<<<dim3(16, 16, 4), 256, 0, stream>>>(raw, sA, sR, sI, subA, subR, subI, rho);

    gemm_bt<256, false, true, float><<<dim3(M_ / 256, D_ / 256), 512, 0, stream>>>(
        rho, wrb, nullptr, rs, out, M_, D_, DK2_);
}